// Round 2
// baseline (10712.679 us; speedup 1.0000x reference)
//
#include <hip/hip_runtime.h>
#include <math.h>

#define NB 256     // batch
#define NH 2048    // hidden
#define ND 8       // state dim
#define NI 16      // 2*ND encoded features
#define NT 128     // seq len
#define NO 4       // outputs
#define KC 64      // k chunk
#define TB 32      // tile b per block
#define TH 64      // tile h per block
#define LP 68      // padded LDS row stride (floats)
#define NTHR 256

// ws float offsets
#define OFF_ZBUF 0                         // [2][NB][NH] spike double buffer
#define OFF_XS   (2*NB*NH)                 // [NT][NB][NI] encoder spikes
#define OFF_V    (OFF_XS + NT*NB*NI)       // [NB][NH] membrane
#define OFF_I    (OFF_V + NB*NH)           // [NB][NH] synapse current
#define OFF_PIO  (OFF_I + NB*NH)           // [2][NB][32][NO] readout partials
#define OFF_VIO  (OFF_PIO + 2*NB*32*NO)    // [3][NB*NO] vo, io, mx
// total = 2,690,048 floats = 10.3 MB

__global__ __launch_bounds__(NTHR) void k_init(const float* __restrict__ x,
                                               float* __restrict__ ws) {
    const int g = blockIdx.x * NTHR + threadIdx.x;   // 65536 threads
    float* zbuf = ws + OFF_ZBUF;
    float* xs   = ws + OFF_XS;
    float* vst  = ws + OFF_V;
    float* ist  = ws + OFF_I;
    float* vio  = ws + OFF_VIO;

    #pragma unroll
    for (int r = 0; r < 8; ++r) zbuf[g + r * 65536] = 0.0f;  // z buffer 0 (read at t=0)
    #pragma unroll
    for (int r = 0; r < 8; ++r) vst[g + r * 65536] = 0.0f;
    #pragma unroll
    for (int r = 0; r < 8; ++r) ist[g + r * 65536] = 0.0f;

    if (g < 3 * NB * NO) vio[g] = (g < 2 * NB * NO) ? 0.0f : -3.0e38f;

    // encoder: one thread per (b, ci) cell, sequential over 128 steps
    if (g < NB * NI) {
        const int b = g >> 4, ci = g & 15;
        float xv = x[b * ND + (ci & 7)];
        float c = (ci < 8) ? __fmul_rn(50.0f, xv) : __fmul_rn(-50.0f, xv);
        c = fmaxf(c, 0.0f);
        float ev = 0.0f;
        for (int t = 0; t < NT; ++t) {
            ev = __fadd_rn(ev, __fmul_rn(0.1f, __fsub_rn(c, ev)));
            float z = (__fsub_rn(ev, 1.0f) > 0.0f) ? 1.0f : 0.0f;
            xs[t * (NB * NI) + g] = z;
            ev = (z > 0.0f) ? 0.0f : ev;
        }
    }
}

__global__ __launch_bounds__(NTHR) void k_step(const float* __restrict__ w_in,
                                               const float* __restrict__ w_rec,
                                               const float* __restrict__ w_out,
                                               float* __restrict__ ws, int t) {
    __shared__ float w_lds[TH * LP];
    __shared__ float z_lds[TB * LP];
    __shared__ float w_in_lds[TH * 17];
    __shared__ float xs_lds[TB * 17];

    const int tid = threadIdx.x;
    const int beta = blockIdx.x;
    const int bt = beta >> 5, ht = beta & 31;
    const int b0 = bt * TB, h0 = ht * TH;

    float* zbuf = ws + OFF_ZBUF;
    const float* xs = ws + OFF_XS;
    float* vst = ws + OFF_V;
    float* ist = ws + OFF_I;
    float* pio = ws + OFF_PIO;
    float* vio = ws + OFF_VIO;

    const float* zr = zbuf + (t & 1) * (NB * NH);
    float* zw = zbuf + ((t + 1) & 1) * (NB * NH);
    float* pw = pio + (t & 1) * (NB * 32 * NO);

    // readout update for step t-1 (partials completed by previous kernel; stream-ordered)
    const int g = beta * NTHR + tid;
    if (t > 0 && g < NB * NO) {
        const float* pr = pio + ((t - 1) & 1) * (NB * 32 * NO);
        float s = 0.0f;
        #pragma unroll
        for (int hb = 0; hb < 32; ++hb) s += pr[((g >> 2) * 32 + hb) * NO + (g & 3)];
        float vo = vio[g], io = vio[NB * NO + g], mx = vio[2 * NB * NO + g];
        float von = __fadd_rn(vo, __fmul_rn(0.1f, __fsub_rn(io, vo)));  // uses OLD io
        io = __fadd_rn(__fmul_rn(io, 0.8f), s);
        vio[g] = von;
        vio[NB * NO + g] = io;
        vio[2 * NB * NO + g] = fmaxf(mx, von);
    }

    // stage w_in tile + this step's encoder spikes
    #pragma unroll
    for (int r = 0; r < 4; ++r) {
        int idx = tid + r * NTHR;
        int hl = idx >> 4, i = idx & 15;
        w_in_lds[hl * 17 + i] = w_in[(h0 + hl) * NI + i];
    }
    #pragma unroll
    for (int r = 0; r < 2; ++r) {
        int idx = tid + r * NTHR;
        int bl = idx >> 4, ci = idx & 15;
        xs_lds[bl * 17 + ci] = xs[t * (NB * NI) + (b0 + bl) * NI + ci];
    }

    const int bl0 = (tid >> 4) * 2;   // 0,2,..,30
    const int hl0 = tid & 15;
    float acc[2][4];
    #pragma unroll
    for (int a = 0; a < 2; ++a)
        #pragma unroll
        for (int j = 0; j < 4; ++j) acc[a][j] = 0.0f;

    // recurrent GEMM: acc[b][h] = sum_k z_prev[b,k] * w_rec[h,k]
    for (int kc = 0; kc < NH; kc += KC) {
        __syncthreads();
        #pragma unroll
        for (int r = 0; r < 4; ++r) {
            int idx = tid + r * NTHR;
            int hl = idx >> 4, k4 = idx & 15;
            float4 wv = *reinterpret_cast<const float4*>(&w_rec[(h0 + hl) * NH + kc + k4 * 4]);
            *reinterpret_cast<float4*>(&w_lds[hl * LP + k4 * 4]) = wv;
        }
        #pragma unroll
        for (int r = 0; r < 2; ++r) {
            int idx = tid + r * NTHR;
            int bl = idx >> 4, k4 = idx & 15;
            float4 zv = *reinterpret_cast<const float4*>(&zr[(b0 + bl) * NH + kc + k4 * 4]);
            *reinterpret_cast<float4*>(&z_lds[bl * LP + k4 * 4]) = zv;
        }
        __syncthreads();
        #pragma unroll
        for (int k4 = 0; k4 < 16; ++k4) {
            float4 za = *reinterpret_cast<const float4*>(&z_lds[bl0 * LP + k4 * 4]);
            float4 zb = *reinterpret_cast<const float4*>(&z_lds[(bl0 + 1) * LP + k4 * 4]);
            #pragma unroll
            for (int j = 0; j < 4; ++j) {
                float4 wv = *reinterpret_cast<const float4*>(&w_lds[(hl0 + 16 * j) * LP + k4 * 4]);
                acc[0][j] = fmaf(za.x, wv.x, acc[0][j]);
                acc[0][j] = fmaf(za.y, wv.y, acc[0][j]);
                acc[0][j] = fmaf(za.z, wv.z, acc[0][j]);
                acc[0][j] = fmaf(za.w, wv.w, acc[0][j]);
                acc[1][j] = fmaf(zb.x, wv.x, acc[1][j]);
                acc[1][j] = fmaf(zb.y, wv.y, acc[1][j]);
                acc[1][j] = fmaf(zb.z, wv.z, acc[1][j]);
                acc[1][j] = fmaf(zb.w, wv.w, acc[1][j]);
            }
        }
    }

    // LIF neuron update (exact reference op order), persist state, write spikes
    float zi[2][4];
    #pragma unroll
    for (int a = 0; a < 2; ++a) {
        int bl = bl0 + a;
        #pragma unroll
        for (int j = 0; j < 4; ++j) {
            int hl = hl0 + 16 * j;
            int gidx = (b0 + bl) * NH + h0 + hl;
            float vv = vst[gidx], ii = ist[gidx];
            float c = 0.0f;
            #pragma unroll
            for (int i = 0; i < NI; ++i)
                c = fmaf(xs_lds[bl * 17 + i], w_in_lds[hl * 17 + i], c);
            float vd = __fadd_rn(vv, __fmul_rn(0.1f, __fsub_rn(ii, vv)));
            float zn = (__fsub_rn(vd, 1.0f) > 0.0f) ? 1.0f : 0.0f;
            vst[gidx] = (zn > 0.0f) ? 0.0f : vd;
            ist[gidx] = __fadd_rn(__fadd_rn(__fmul_rn(ii, 0.8f), c), acc[a][j]);
            zi[a][j] = zn;
            zw[gidx] = zn;
        }
    }

    // readout partials for this step: sum over this block's 64 h per (b, o)
    #pragma unroll
    for (int o = 0; o < NO; ++o) {
        float s0 = 0.0f, s1 = 0.0f;
        #pragma unroll
        for (int j = 0; j < 4; ++j) {
            float wv = w_out[o * NH + h0 + hl0 + 16 * j];
            s0 = fmaf(zi[0][j], wv, s0);
            s1 = fmaf(zi[1][j], wv, s1);
        }
        #pragma unroll
        for (int msk = 1; msk < 16; msk <<= 1) {
            s0 += __shfl_xor(s0, msk, 64);
            s1 += __shfl_xor(s1, msk, 64);
        }
        if (hl0 == 0) {
            pw[((b0 + bl0) * 32 + ht) * NO + o] = s0;
            pw[((b0 + bl0 + 1) * 32 + ht) * NO + o] = s1;
        }
    }
}

__global__ __launch_bounds__(NTHR) void k_final(float* __restrict__ ws,
                                                float* __restrict__ out) {
    const int g = blockIdx.x * NTHR + threadIdx.x;   // 1024 threads
    float* pio = ws + OFF_PIO;
    float* vio = ws + OFF_VIO;
    if (g >= NB * NO) return;

    const float* pr = pio + ((NT - 1) & 1) * (NB * 32 * NO);
    float s = 0.0f;
    #pragma unroll
    for (int hb = 0; hb < 32; ++hb) s += pr[((g >> 2) * 32 + hb) * NO + (g & 3)];
    float vo = vio[g], io = vio[NB * NO + g], mx = vio[2 * NB * NO + g];
    float von = __fadd_rn(vo, __fmul_rn(0.1f, __fsub_rn(io, vo)));
    mx = fmaxf(mx, von);
    (void)s;  // io jump at the last step never feeds an observed voltage

    float mm = fmaxf(mx, __shfl_xor(mx, 1, 64));
    mm = fmaxf(mm, __shfl_xor(mm, 2, 64));
    float e = expf(__fsub_rn(mx, mm));
    float es = e;
    es += __shfl_xor(es, 1, 64);
    es += __shfl_xor(es, 2, 64);
    out[g] = e / es;
}

extern "C" void kernel_launch(void* const* d_in, const int* in_sizes, int n_in,
                              void* d_out, int out_size, void* d_ws, size_t ws_size,
                              hipStream_t stream) {
    const float* x     = (const float*)d_in[0];
    const float* w_in  = (const float*)d_in[1];
    const float* w_rec = (const float*)d_in[2];
    const float* w_out = (const float*)d_in[3];
    float* out = (float*)d_out;
    float* ws  = (float*)d_ws;

    k_init<<<256, NTHR, 0, stream>>>(x, ws);
    for (int t = 0; t < NT; ++t)
        k_step<<<256, NTHR, 0, stream>>>(w_in, w_rec, w_out, ws, t);
    k_final<<<4, NTHR, 0, stream>>>(ws, out);
}

// Round 3
// 3763.121 us; speedup vs baseline: 2.8468x; 2.8468x over previous
//
#include <hip/hip_runtime.h>
#include <math.h>

#define NB 256
#define NH 2048
#define ND 8
#define NI 16
#define NT 128
#define NO 4
#define KP 2176          // padded K: 2048 rec + 16 in + 112 zeros
#define NTHR 256

typedef __attribute__((ext_vector_type(8))) short bf16x8;
typedef __attribute__((ext_vector_type(4))) float f32x4;

// ---- ws byte offsets ----
#define OFF_W3   0u                                  // 3 x [NH][KP] bf16 (hi, mid, lo)
#define SZ_W3    (3u*NH*KP*2u)
#define OFF_ZB   (OFF_W3 + SZ_W3)                    // 2 x [NB][KP] bf16 (z | xs | 0)
#define SZ_ZB    (2u*NB*KP*2u)
#define OFF_XS   (OFF_ZB + SZ_ZB)                    // [NT][NB][NI] bf16 encoder spikes
#define SZ_XS    ((unsigned)NT*NB*NI*2u)
#define OFF_V    (OFF_XS + SZ_XS)                    // [NB][NH] f32
#define SZ_V     ((unsigned)NB*NH*4u)
#define OFF_I    (OFF_V + SZ_V)
#define OFF_PIO  (OFF_I + SZ_V)                      // 2 x [NB][64][NO] f32
#define SZ_PIO   (2u*NB*64u*NO*4u)
#define OFF_VIO  (OFF_PIO + SZ_PIO)                  // vo[1024], io[1024], mx[1024] f32

__device__ __forceinline__ ushort f2bf(float f) {   // RN-even f32 -> bf16 bits
    unsigned u = __float_as_uint(f);
    unsigned r = (u + 0x7FFFu + ((u >> 16) & 1u)) >> 16;
    return (ushort)r;
}
__device__ __forceinline__ float bf2f(ushort b) {
    return __uint_as_float(((unsigned)b) << 16);
}

// one-time: pack w = hi+mid+lo bf16 splits, K-extended with w_in and zero pad
__global__ __launch_bounds__(NTHR) void k_pack(const float* __restrict__ w_rec,
                                               const float* __restrict__ w_in,
                                               char* __restrict__ wsb) {
    int idx = blockIdx.x * NTHR + threadIdx.x;
    if (idx >= NH * KP) return;
    int h = idx / KP, k = idx - h * KP;
    float wv = 0.0f;
    if (k < NH) wv = w_rec[h * NH + k];
    else if (k < NH + NI) wv = w_in[h * NI + (k - NH)];
    ushort* w3 = (ushort*)(wsb + OFF_W3);
    ushort hi = f2bf(wv);
    float r1 = wv - bf2f(hi);
    ushort mid = f2bf(r1);
    float r2 = r1 - bf2f(mid);
    ushort lo = f2bf(r2);
    w3[idx] = hi;
    w3[NH * KP + idx] = mid;
    w3[2 * NH * KP + idx] = lo;
}

// one-time: zero state/spike buffers, run 128-step LIF encoder
__global__ __launch_bounds__(NTHR) void k_init(const float* __restrict__ x,
                                               char* __restrict__ wsb) {
    const int g = blockIdx.x * NTHR + threadIdx.x;   // 65536 threads
    unsigned* zb = (unsigned*)(wsb + OFF_ZB);        // 556544 uints
    float* vst = (float*)(wsb + OFF_V);
    float* ist = (float*)(wsb + OFF_I);
    float* vio = (float*)(wsb + OFF_VIO);
    ushort* xsp = (ushort*)(wsb + OFF_XS);

    #pragma unroll
    for (int r = 0; r < 9; ++r) {
        unsigned off = (unsigned)g + r * 65536u;
        if (off < (SZ_ZB / 4u)) zb[off] = 0u;
    }
    #pragma unroll
    for (int r = 0; r < 8; ++r) vst[g + r * 65536] = 0.0f;
    #pragma unroll
    for (int r = 0; r < 8; ++r) ist[g + r * 65536] = 0.0f;
    if (g < 3072) vio[g] = (g < 2048) ? 0.0f : -3.0e38f;

    if (g < NB * NI) {   // encoder cell (b, ci)
        const int b = g >> 4, ci = g & 15;
        float xv = x[b * ND + (ci & 7)];
        float c = (ci < 8) ? __fmul_rn(50.0f, xv) : __fmul_rn(-50.0f, xv);
        c = fmaxf(c, 0.0f);
        float ev = 0.0f;
        for (int t = 0; t < NT; ++t) {
            ev = __fadd_rn(ev, __fmul_rn(0.1f, __fsub_rn(c, ev)));
            float z = (__fsub_rn(ev, 1.0f) > 0.0f) ? 1.0f : 0.0f;
            xsp[t * (NB * NI) + g] = (z > 0.0f) ? (ushort)0x3F80 : (ushort)0;
            ev = (z > 0.0f) ? 0.0f : ev;
        }
    }
}

// one-time: drop xs[0] into z-buffer 0's extension columns (after zeroing)
__global__ __launch_bounds__(NTHR) void k_init2(char* __restrict__ wsb) {
    const int g = blockIdx.x * NTHR + threadIdx.x;   // 4096
    ushort* zb0 = (ushort*)(wsb + OFF_ZB);
    const ushort* xsp = (const ushort*)(wsb + OFF_XS);
    if (g < NB * NI) zb0[(g >> 4) * KP + NH + (g & 15)] = xsp[g];
}

__global__ __launch_bounds__(NTHR) void k_step(const float* __restrict__ w_out,
                                               char* __restrict__ wsb, int t) {
    __shared__ float red[4 * 64 * 33];    // 4 k-split partials, [64b][33-padded 32h]
    __shared__ float w_out_lds[128];

    const int tid = threadIdx.x;
    const int beta = blockIdx.x;
    const int xcd = beta & 7, j = beta >> 3;
    const int ht = xcd * 8 + (j & 7);     // 0..63  (h-tile, XCD-contiguous)
    const int bt = j >> 3;                // 0..3
    const int b0 = bt * 64, h0 = ht * 32;

    const ushort* w3 = (const ushort*)(wsb + OFF_W3);
    ushort* zb = (ushort*)(wsb + OFF_ZB);
    const ushort* xsp = (const ushort*)(wsb + OFF_XS);
    float* vst = (float*)(wsb + OFF_V);
    float* ist = (float*)(wsb + OFF_I);
    float* pio = (float*)(wsb + OFF_PIO);
    float* vio = (float*)(wsb + OFF_VIO);

    const ushort* zr = zb + (t & 1) * (NB * KP);
    ushort* zw = zb + ((t + 1) & 1) * (NB * KP);

    // LI readout update for step t-1 (stream-ordered: pio[t-1] complete)
    const int g = beta * NTHR + tid;
    if (t > 0 && g < NB * NO) {
        const float* pr = pio + ((t - 1) & 1) * (NB * 64 * NO);
        const int b = g >> 2, o = g & 3;
        float s = 0.0f;
        #pragma unroll
        for (int jj = 0; jj < 64; ++jj) s += pr[(b * 64 + jj) * NO + o];
        float vo = vio[g], io = vio[1024 + g], mx = vio[2048 + g];
        float von = __fadd_rn(vo, __fmul_rn(0.1f, __fsub_rn(io, vo)));  // old io
        io = __fadd_rn(__fmul_rn(io, 0.8f), s);
        vio[g] = von; vio[1024 + g] = io; vio[2048 + g] = fmaxf(mx, von);
    }

    // copy xs[t+1] into next z-buffer's extension columns
    if (ht == 0 && t + 1 < NT) {
        #pragma unroll
        for (int e = 0; e < 4; ++e) {
            int v = e * NTHR + tid;
            int bl = v >> 4, ci = v & 15;
            zw[(b0 + bl) * KP + NH + ci] = xsp[(t + 1) * (NB * NI) + (b0 + bl) * NI + ci];
        }
    }
    if (tid < 128) w_out_lds[tid] = w_out[(tid >> 5) * NH + h0 + (tid & 31)];

    // ---- MFMA GEMM: acc[b][h] = sum_k A[b,k]*W[h,k], 3-split, K split 4x across waves
    const int w = tid >> 6, lane = tid & 63;
    const int lh = lane & 15, lk = lane >> 4;
    const int k0w = w * 544;              // 17 ksteps of K=32 per wave

    f32x4 acc[4][2];
    #pragma unroll
    for (int rb = 0; rb < 4; ++rb)
        #pragma unroll
        for (int hb = 0; hb < 2; ++hb) acc[rb][hb] = (f32x4){0.f, 0.f, 0.f, 0.f};

    const ushort* zA = zr + (unsigned)(b0 + lh) * KP + k0w + lk * 8;
    const ushort* wB = w3 + (unsigned)(h0 + lh) * KP + k0w + lk * 8;

    #pragma unroll 2
    for (int kk = 0; kk < 17; ++kk) {
        const int ko = kk * 32;
        bf16x8 a[4];
        #pragma unroll
        for (int rb = 0; rb < 4; ++rb)
            a[rb] = *(const bf16x8*)(zA + rb * 16 * KP + ko);
        #pragma unroll
        for (int hb = 0; hb < 2; ++hb) {
            #pragma unroll
            for (int s = 0; s < 3; ++s) {
                bf16x8 bf = *(const bf16x8*)(wB + (unsigned)s * NH * KP + hb * 16 * KP + ko);
                #pragma unroll
                for (int rb = 0; rb < 4; ++rb)
                    acc[rb][hb] = __builtin_amdgcn_mfma_f32_16x16x32_bf16(a[rb], bf, acc[rb][hb], 0, 0, 0);
            }
        }
    }

    // partials -> LDS (C/D layout: col=lane&15, row=(lane>>4)*4+reg)
    #pragma unroll
    for (int rb = 0; rb < 4; ++rb)
        #pragma unroll
        for (int hb = 0; hb < 2; ++hb)
            #pragma unroll
            for (int r = 0; r < 4; ++r)
                red[w * 2112 + (rb * 16 + lk * 4 + r) * 33 + hb * 16 + lh] = acc[rb][hb][r];
    __syncthreads();

    // reduce 4 k-partials + LIF neuron update (8 elems/thread)
    float zn8[8];
    #pragma unroll
    for (int e = 0; e < 8; ++e) {
        int idx = e * NTHR + tid;
        int bl = idx >> 5, hl = idx & 31;
        int ro = bl * 33 + hl;
        float accv = ((red[ro] + red[2112 + ro]) + red[2 * 2112 + ro]) + red[3 * 2112 + ro];
        int gidx = (b0 + bl) * NH + h0 + hl;
        float vv = vst[gidx], ii = ist[gidx];
        float vd = __fadd_rn(vv, __fmul_rn(0.1f, __fsub_rn(ii, vv)));
        float zn = (__fsub_rn(vd, 1.0f) > 0.0f) ? 1.0f : 0.0f;
        vst[gidx] = (zn > 0.0f) ? 0.0f : vd;
        ist[gidx] = __fadd_rn(__fmul_rn(ii, 0.8f), accv);
        zw[(b0 + bl) * KP + h0 + hl] = (zn > 0.0f) ? (ushort)0x3F80 : (ushort)0;
        zn8[e] = zn;
    }
    __syncthreads();
    #pragma unroll
    for (int e = 0; e < 8; ++e) {
        int idx = e * NTHR + tid;
        red[(idx >> 5) * 33 + (idx & 31)] = zn8[e];
    }
    __syncthreads();

    // readout partial: sum over this block's 32 h per (b, o)
    {
        const int b = tid >> 2, o = tid & 3;
        float s = 0.0f;
        #pragma unroll
        for (int h = 0; h < 32; ++h)
            s = fmaf(red[b * 33 + h], w_out_lds[o * 32 + h], s);
        float* pw = pio + (t & 1) * (NB * 64 * NO);
        pw[((b0 + b) * 64 + ht) * NO + o] = s;
    }
}

__global__ __launch_bounds__(NTHR) void k_final(char* __restrict__ wsb,
                                                float* __restrict__ out) {
    const int g = blockIdx.x * NTHR + threadIdx.x;
    if (g >= NB * NO) return;
    float* vio = (float*)(wsb + OFF_VIO);
    float vo = vio[g], io = vio[1024 + g], mx = vio[2048 + g];
    float von = __fadd_rn(vo, __fmul_rn(0.1f, __fsub_rn(io, vo)));
    mx = fmaxf(mx, von);

    float mm = fmaxf(mx, __shfl_xor(mx, 1, 64));
    mm = fmaxf(mm, __shfl_xor(mm, 2, 64));
    float e = expf(__fsub_rn(mx, mm));
    float es = e;
    es += __shfl_xor(es, 1, 64);
    es += __shfl_xor(es, 2, 64);
    out[g] = e / es;
}

extern "C" void kernel_launch(void* const* d_in, const int* in_sizes, int n_in,
                              void* d_out, int out_size, void* d_ws, size_t ws_size,
                              hipStream_t stream) {
    const float* x     = (const float*)d_in[0];
    const float* w_in  = (const float*)d_in[1];
    const float* w_rec = (const float*)d_in[2];
    const float* w_out = (const float*)d_in[3];
    float* out = (float*)d_out;
    char* wsb  = (char*)d_ws;

    k_pack<<<(NH * KP + NTHR - 1) / NTHR, NTHR, 0, stream>>>(w_rec, w_in, wsb);
    k_init<<<256, NTHR, 0, stream>>>(x, wsb);
    k_init2<<<16, NTHR, 0, stream>>>(wsb);
    for (int t = 0; t < NT; ++t)
        k_step<<<256, NTHR, 0, stream>>>(w_out, wsb, t);
    k_final<<<4, NTHR, 0, stream>>>(wsb, out);
}

// Round 5
// 1926.636 us; speedup vs baseline: 5.5603x; 1.9532x over previous
//
#include <hip/hip_runtime.h>
#include <math.h>

#define NB 256
#define NH 2048
#define ND 8
#define NI 16
#define NT 128
#define NO 4
#define KP 2176          // padded K: 2048 rec + 16 in + 112 zeros
#define KK 68            // KP/32 ksteps
#define NTHR 512

typedef __attribute__((ext_vector_type(8))) short bf16x8;
typedef __attribute__((ext_vector_type(8))) unsigned short ushort8;
typedef __attribute__((ext_vector_type(4))) float f32x4;

// ---- ws byte offsets ----
// W4: 3 splits x [128 h16][68 kk][64 lane][8] bf16 (fragment-linear)
#define OFF_W4   0u
#define SZ_W4    (3u*128u*KK*512u*2u)               // 26,738,688
#define ZBUF_E   (16u*KK*512u)                      // 557,056 ushorts per buffer
#define OFF_ZB   (OFF_W4 + SZ_W4)                   // 2 x Z4[16 b16][68 kk][64 lane][8]
#define SZ_ZB    (2u*ZBUF_E*2u)
#define OFF_XS   (OFF_ZB + SZ_ZB)                   // [NT][NB][NI] bf16 encoder spikes
#define SZ_XS    ((unsigned)NT*NB*NI*2u)
#define OFF_V    (OFF_XS + SZ_XS)                   // [NB][NH] f32
#define SZ_V     ((unsigned)NB*NH*4u)
#define OFF_I    (OFF_V + SZ_V)
#define OFF_PIO  (OFF_I + SZ_V)                     // 2 x [NB][64][NO] f32
#define SZ_PIO   (2u*NB*64u*NO*4u)
#define OFF_VIO  (OFF_PIO + SZ_PIO)                 // vo[1024], io[1024], mx[1024]

__device__ __forceinline__ ushort f2bf(float f) {
    unsigned u = __float_as_uint(f);
    unsigned r = (u + 0x7FFFu + ((u >> 16) & 1u)) >> 16;
    return (ushort)r;
}
__device__ __forceinline__ float bf2f(ushort b) {
    return __uint_as_float(((unsigned)b) << 16);
}
// fragment-linear index (in ushorts) for s=0; s-stride = 128*KK*512
__device__ __forceinline__ unsigned w4idx(int h, int k) {
    return (((unsigned)(h >> 4)) * KK + (unsigned)(k >> 5)) * 512u
           + (((unsigned)(k >> 3) & 3u) * 128u) + ((unsigned)(h & 15) * 8u)
           + ((unsigned)k & 7u);
}

__global__ __launch_bounds__(256) void k_pack(const float* __restrict__ w_rec,
                                              const float* __restrict__ w_in,
                                              char* __restrict__ wsb) {
    int idx = blockIdx.x * 256 + threadIdx.x;
    if (idx >= NH * KP) return;
    int h = idx / KP, k = idx - h * KP;
    float wv = 0.0f;
    if (k < NH) wv = w_rec[h * NH + k];
    else if (k < NH + NI) wv = w_in[h * NI + (k - NH)];
    ushort* w4 = (ushort*)(wsb + OFF_W4);
    ushort hi = f2bf(wv);
    float r1 = wv - bf2f(hi);
    ushort mid = f2bf(r1);
    float r2 = r1 - bf2f(mid);
    ushort lo = f2bf(r2);
    unsigned base = w4idx(h, k);
    const unsigned sstr = 128u * KK * 512u;
    w4[base] = hi;
    w4[sstr + base] = mid;
    w4[2u * sstr + base] = lo;
}

__global__ __launch_bounds__(256) void k_init(const float* __restrict__ x,
                                              char* __restrict__ wsb) {
    const int g = blockIdx.x * 256 + threadIdx.x;   // 65536 threads
    unsigned* zb32 = (unsigned*)(wsb + OFF_ZB);
    float* vst = (float*)(wsb + OFF_V);
    float* ist = (float*)(wsb + OFF_I);
    float* vio = (float*)(wsb + OFF_VIO);
    ushort* xsp = (ushort*)(wsb + OFF_XS);

    #pragma unroll
    for (int r = 0; r < 9; ++r) {
        unsigned off = (unsigned)g + (unsigned)r * 65536u;
        if (off < (SZ_ZB / 4u)) zb32[off] = 0u;
    }
    #pragma unroll
    for (int r = 0; r < 8; ++r) vst[g + r * 65536] = 0.0f;
    #pragma unroll
    for (int r = 0; r < 8; ++r) ist[g + r * 65536] = 0.0f;
    if (g < 3072) vio[g] = (g < 2048) ? 0.0f : -3.0e38f;

    if (g < NB * NI) {   // encoder cell (b, ci)
        const int b = g >> 4, ci = g & 15;
        float xv = x[b * ND + (ci & 7)];
        float c = (ci < 8) ? __fmul_rn(50.0f, xv) : __fmul_rn(-50.0f, xv);
        c = fmaxf(c, 0.0f);
        float ev = 0.0f;
        for (int t = 0; t < NT; ++t) {
            ev = __fadd_rn(ev, __fmul_rn(0.1f, __fsub_rn(c, ev)));
            float z = (__fsub_rn(ev, 1.0f) > 0.0f) ? 1.0f : 0.0f;
            xsp[t * (NB * NI) + g] = (z > 0.0f) ? (ushort)0x3F80 : (ushort)0;
            ev = (z > 0.0f) ? 0.0f : ev;
        }
    }
}

// xs[0] -> Z4 buffer 0 extension (kk=64, k-quads 0/1)
__global__ __launch_bounds__(256) void k_init2(char* __restrict__ wsb) {
    const int g = blockIdx.x * 256 + threadIdx.x;   // 512 threads
    if (g >= NB * 2) return;
    ushort* zb0 = (ushort*)(wsb + OFF_ZB);
    const ushort* xsp = (const ushort*)(wsb + OFF_XS);
    int bl = g >> 1, c = g & 1;
    uint4 xv = *(const uint4*)(xsp + bl * 16 + c * 8);
    unsigned dst = ((((unsigned)(bl >> 4)) * KK + 64u) * 64u
                    + (unsigned)c * 16u + (unsigned)(bl & 15)) * 8u;
    *(uint4*)(zb0 + dst) = xv;
}

__global__ __launch_bounds__(NTHR, 2) void k_step(const float* __restrict__ w_out,
                                                  char* __restrict__ wsb, int t) {
    __shared__ float red[4 * 64 * 34];   // 4 k-partial buffers (two-phase reduce)
    __shared__ float z_s[64 * 34];
    __shared__ float w_out_lds[128];     // total LDS = 44,032 B

    const int tid = threadIdx.x;
    const int beta = blockIdx.x;
    const int xcd = beta & 7, jb = beta >> 3;
    const int ht = xcd * 8 + (jb & 7);   // 0..63 (h-tile, XCD-contiguous weights)
    const int bt = jb >> 3;              // 0..3
    const int b0 = bt * 64, h0 = ht * 32;

    const ushort* w4 = (const ushort*)(wsb + OFF_W4);
    ushort* zb = (ushort*)(wsb + OFF_ZB);
    const ushort* xsp = (const ushort*)(wsb + OFF_XS);
    float* vst = (float*)(wsb + OFF_V);
    float* ist = (float*)(wsb + OFF_I);
    float* pio = (float*)(wsb + OFF_PIO);
    float* vio = (float*)(wsb + OFF_VIO);

    const ushort* zr = zb + (t & 1) * ZBUF_E;
    ushort* zw = zb + ((t + 1) & 1) * ZBUF_E;

    // LI readout update for step t-1 (stream-ordered)
    const int g = beta * NTHR + tid;
    if (t > 0 && g < NB * NO) {
        const float* pr = pio + ((t - 1) & 1) * (NB * 64 * NO);
        const int b = g >> 2, o = g & 3;
        float s = 0.0f;
        #pragma unroll
        for (int jj = 0; jj < 64; ++jj) s += pr[(b * 64 + jj) * NO + o];
        float vo = vio[g], io = vio[1024 + g], mx = vio[2048 + g];
        float von = __fadd_rn(vo, __fmul_rn(0.1f, __fsub_rn(io, vo)));  // old io
        io = __fadd_rn(__fmul_rn(io, 0.8f), s);
        vio[g] = von; vio[1024 + g] = io; vio[2048 + g] = fmaxf(mx, von);
    }

    // xs[t+1] -> next Z4 extension (kk=64, k-quads 0/1)
    if (ht == 0 && t + 1 < NT && tid < 128) {
        int bl = tid >> 1, c = tid & 1;
        int bg = b0 + bl;
        uint4 xv = *(const uint4*)(xsp + (t + 1) * (NB * NI) + bg * 16 + c * 8);
        unsigned dst = ((((unsigned)(bg >> 4)) * KK + 64u) * 64u
                        + (unsigned)c * 16u + (unsigned)(bg & 15)) * 8u;
        *(uint4*)(zw + dst) = xv;
    }
    if (tid < 128) w_out_lds[tid] = w_out[(tid >> 5) * NH + h0 + (tid & 31)];

    // ---- MFMA GEMM: waves split K by kk%8; each wave keeps full 64b x 32h tile
    const int w = tid >> 6, lane = tid & 63;
    const unsigned h16a = (unsigned)(h0 >> 4);
    const unsigned sstr = 128u * KK * 512u;

    f32x4 acc[4][2];
    #pragma unroll
    for (int rb = 0; rb < 4; ++rb)
        #pragma unroll
        for (int hb = 0; hb < 2; ++hb) acc[rb][hb] = (f32x4){0.f, 0.f, 0.f, 0.f};

    #pragma unroll 2
    for (int kk = w; kk < KK; kk += 8) {
        bf16x8 a[4];
        #pragma unroll
        for (int rb = 0; rb < 4; ++rb) {
            unsigned off = (((unsigned)(bt * 4 + rb) * KK + (unsigned)kk) * 64u
                            + (unsigned)lane) * 8u;
            a[rb] = *(const bf16x8*)(zr + off);
        }
        #pragma unroll
        for (int s = 0; s < 3; ++s) {
            #pragma unroll
            for (int hb = 0; hb < 2; ++hb) {
                unsigned off = (unsigned)s * sstr
                             + (((h16a + (unsigned)hb) * KK + (unsigned)kk) * 64u
                                + (unsigned)lane) * 8u;
                bf16x8 bf = *(const bf16x8*)(w4 + off);
                #pragma unroll
                for (int rb = 0; rb < 4; ++rb)
                    acc[rb][hb] = __builtin_amdgcn_mfma_f32_16x16x32_bf16(
                        a[rb], bf, acc[rb][hb], 0, 0, 0);
            }
        }
    }

    // two-phase cross-wave reduce (C/D: col=lane&15 (h), row=(lane>>4)*4+reg (b))
    const int lk = lane >> 4, lh = lane & 15;
    if (w >= 4) {
        #pragma unroll
        for (int rb = 0; rb < 4; ++rb)
            #pragma unroll
            for (int hb = 0; hb < 2; ++hb)
                #pragma unroll
                for (int r = 0; r < 4; ++r)
                    red[(w - 4) * 2176 + (rb * 16 + lk * 4 + r) * 34 + hb * 16 + lh]
                        = acc[rb][hb][r];
    }
    __syncthreads();
    if (w < 4) {
        #pragma unroll
        for (int rb = 0; rb < 4; ++rb)
            #pragma unroll
            for (int hb = 0; hb < 2; ++hb)
                #pragma unroll
                for (int r = 0; r < 4; ++r) {
                    int ro = w * 2176 + (rb * 16 + lk * 4 + r) * 34 + hb * 16 + lh;
                    red[ro] = acc[rb][hb][r] + red[ro];
                }
    }
    __syncthreads();

    // reduce 4 buffers + LIF update (4 elems/thread)
    #pragma unroll
    for (int e = 0; e < 4; ++e) {
        int idx = e * NTHR + tid;
        int bl = idx >> 5, hl = idx & 31;
        int ro = bl * 34 + hl;
        float accv = ((red[ro] + red[2176 + ro]) + red[2 * 2176 + ro]) + red[3 * 2176 + ro];
        int gidx = (b0 + bl) * NH + h0 + hl;
        float vv = vst[gidx], ii = ist[gidx];
        float vd = __fadd_rn(vv, __fmul_rn(0.1f, __fsub_rn(ii, vv)));
        float zn = (__fsub_rn(vd, 1.0f) > 0.0f) ? 1.0f : 0.0f;
        vst[gidx] = (zn > 0.0f) ? 0.0f : vd;
        ist[gidx] = __fadd_rn(__fmul_rn(ii, 0.8f), accv);
        z_s[ro] = zn;
    }
    __syncthreads();

    if (tid < 256) {
        // spikes -> Z4 (fragment-linear; this block owns kk=ht for its b16 range)
        int b = tid >> 2, c = tid & 3;
        int bg = b0 + b;
        ushort8 zv8;
        #pragma unroll
        for (int jj = 0; jj < 8; ++jj)
            zv8[jj] = (z_s[b * 34 + c * 8 + jj] > 0.5f) ? (ushort)0x3F80 : (ushort)0;
        unsigned dst = ((((unsigned)(bg >> 4)) * KK + (unsigned)ht) * 64u
                        + (unsigned)c * 16u + (unsigned)(bg & 15)) * 8u;
        *(ushort8*)(zw + dst) = zv8;

        // readout partial: sum over this block's 32 h per (b, o)
        int o = tid & 3;
        float s = 0.0f;
        #pragma unroll
        for (int h = 0; h < 32; ++h)
            s = fmaf(z_s[b * 34 + h], w_out_lds[o * 32 + h], s);
        float* pw = pio + (t & 1) * (NB * 64 * NO);
        pw[((b0 + b) * 64 + ht) * NO + o] = s;
    }
}

__global__ __launch_bounds__(256) void k_final(char* __restrict__ wsb,
                                               float* __restrict__ out) {
    const int g = blockIdx.x * 256 + threadIdx.x;   // needs 1024 threads!
    if (g >= NB * NO) return;
    float* vio = (float*)(wsb + OFF_VIO);
    float vo = vio[g], io = vio[1024 + g], mx = vio[2048 + g];
    float von = __fadd_rn(vo, __fmul_rn(0.1f, __fsub_rn(io, vo)));
    mx = fmaxf(mx, von);

    float mm = fmaxf(mx, __shfl_xor(mx, 1, 64));
    mm = fmaxf(mm, __shfl_xor(mm, 2, 64));
    float e = expf(__fsub_rn(mx, mm));
    float es = e;
    es += __shfl_xor(es, 1, 64);
    es += __shfl_xor(es, 2, 64);
    out[g] = e / es;
}

extern "C" void kernel_launch(void* const* d_in, const int* in_sizes, int n_in,
                              void* d_out, int out_size, void* d_ws, size_t ws_size,
                              hipStream_t stream) {
    const float* x     = (const float*)d_in[0];
    const float* w_in  = (const float*)d_in[1];
    const float* w_rec = (const float*)d_in[2];
    const float* w_out = (const float*)d_in[3];
    float* out = (float*)d_out;
    char* wsb  = (char*)d_ws;

    k_pack<<<(NH * KP + 255) / 256, 256, 0, stream>>>(w_rec, w_in, wsb);
    k_init<<<256, 256, 0, stream>>>(x, wsb);
    k_init2<<<2, 256, 0, stream>>>(wsb);
    for (int t = 0; t < NT; ++t)
        k_step<<<256, NTHR, 0, stream>>>(w_out, wsb, t);
    k_final<<<4, 256, 0, stream>>>(wsb, out);   // 1024 threads: one per (b,o)
}

// Round 6
// 1677.960 us; speedup vs baseline: 6.3843x; 1.1482x over previous
//
#include <hip/hip_runtime.h>
#include <math.h>

#define NB 256
#define NH 2048
#define ND 8
#define NI 16
#define NT 128
#define NO 4
#define KK2 33           // K chunks of 64: 32 rec + 1 (in + pad)  -> K = 2112
#define NTHR 512

typedef __attribute__((ext_vector_type(4))) int i32x4;
typedef __attribute__((ext_vector_type(2))) long i64x2;
typedef __attribute__((ext_vector_type(2))) unsigned u32x2;

// ---- ws byte offsets ----
// W4: 4 i8 splits x [128 h16][33 kk][64 lane][16] (fragment-linear)
#define SSTR     (128u*KK2*1024u)                   // one split = 4,325,376 B
#define OFF_W4   0u
#define SZ_W4    (4u*SSTR)                          // 17,301,504
#define OFF_SC   (OFF_W4 + SZ_W4)                   // inv_scale f32[2048]
#define OFF_SCF  (OFF_SC + 8192u)                   // scale     f32[2048]
#define ZBUF_B   (16u*KK2*1024u)                    // 540,672 B per z buffer
#define OFF_ZB   (OFF_SCF + 8192u)                  // 2 x Z[16 b16][33 kk][64 lane][16] i8
#define SZ_ZB    (2u*ZBUF_B)
#define OFF_XS   (OFF_ZB + SZ_ZB)                   // [NT][NB][NI] i8 encoder spikes
#define SZ_XS    ((unsigned)NT*NB*NI)
#define OFF_V    (OFF_XS + SZ_XS)                   // [NB][NH] f32
#define SZ_V     ((unsigned)NB*NH*4u)
#define OFF_I    (OFF_V + SZ_V)
#define OFF_PIO  (OFF_I + SZ_V)                     // 2 x [NB][64][NO] f32
#define SZ_PIO   (2u*NB*64u*NO*4u)
#define OFF_VIO  (OFF_PIO + SZ_PIO)                 // vo[1024], io[1024], mx[1024]

// per-row scales: s = 30 - exp(rowmax) -> |w*2^s| < 2^30, 4 signed bytes exact
__global__ __launch_bounds__(512) void k_scale(const float* __restrict__ w_rec,
                                               const float* __restrict__ w_in,
                                               char* __restrict__ wsb) {
    const int gt = blockIdx.x * 512 + threadIdx.x;   // 256 blocks -> 2048 waves
    const int h = gt >> 6, lane = gt & 63;
    float m = 0.0f;
    for (int k = lane; k < NH; k += 64) m = fmaxf(m, fabsf(w_rec[h * NH + k]));
    if (lane < 16) m = fmaxf(m, fabsf(w_in[h * NI + lane]));
    #pragma unroll
    for (int d = 1; d < 64; d <<= 1) m = fmaxf(m, __shfl_xor(m, d, 64));
    if (lane == 0) {
        int e;
        frexpf(m, &e);           // m = f*2^e, f in [0.5,1)
        int s = 30 - e;
        ((float*)(wsb + OFF_SCF))[h] = ldexpf(1.0f, s);
        ((float*)(wsb + OFF_SC))[h]  = ldexpf(1.0f, -s);
    }
}

// quantize + split into 4 i8 planes, fragment-linear
__global__ __launch_bounds__(192) void k_pack(const float* __restrict__ w_rec,
                                              const float* __restrict__ w_in,
                                              char* __restrict__ wsb) {
    const int h = blockIdx.x, c = threadIdx.x;       // 2048 blocks, 132 chunks of 16 k
    if (c >= 132) return;
    const float scale = ((const float*)(wsb + OFF_SCF))[h];
    const int k0 = c * 16;
    const int kk = k0 >> 6, q = (k0 >> 4) & 3;
    unsigned pk[4][4] = {{0u,0u,0u,0u},{0u,0u,0u,0u},{0u,0u,0u,0u},{0u,0u,0u,0u}};
    #pragma unroll
    for (int u = 0; u < 16; ++u) {
        int k = k0 + u;
        float wv = 0.0f;
        if (k < NH) wv = w_rec[h * NH + k];
        else if (k < NH + NI) wv = w_in[h * NI + (k - NH)];
        int wq = __float2int_rn(wv * scale);
        int b0_ = (wq << 24) >> 24;  int r = (wq - b0_) >> 8;
        int b1_ = (r << 24) >> 24;   r = (r - b1_) >> 8;
        int b2_ = (r << 24) >> 24;   int b3_ = (r - b2_) >> 8;
        int bs[4] = {b0_, b1_, b2_, b3_};
        #pragma unroll
        for (int sp = 0; sp < 4; ++sp)
            pk[sp][u >> 2] |= ((unsigned)(unsigned char)bs[sp]) << ((u & 3) * 8);
    }
    char* w4 = wsb + OFF_W4;
    unsigned base = (((unsigned)(h >> 4)) * KK2 + (unsigned)kk) * 1024u
                  + ((unsigned)q * 16u + (unsigned)(h & 15)) * 16u;
    #pragma unroll
    for (int sp = 0; sp < 4; ++sp)
        *(i32x4*)(w4 + (unsigned)sp * SSTR + base) = *(const i32x4*)pk[sp];
}

__global__ __launch_bounds__(256) void k_init(const float* __restrict__ x,
                                              char* __restrict__ wsb) {
    const int g = blockIdx.x * 256 + threadIdx.x;   // 65536 threads
    unsigned* zb32 = (unsigned*)(wsb + OFF_ZB);     // 270,336 uints
    float* vst = (float*)(wsb + OFF_V);
    float* ist = (float*)(wsb + OFF_I);
    float* vio = (float*)(wsb + OFF_VIO);
    char* xsp = (char*)(wsb + OFF_XS);

    #pragma unroll
    for (int r = 0; r < 5; ++r) {
        unsigned off = (unsigned)g + (unsigned)r * 65536u;
        if (off < (SZ_ZB / 4u)) zb32[off] = 0u;
    }
    #pragma unroll
    for (int r = 0; r < 8; ++r) vst[g + r * 65536] = 0.0f;
    #pragma unroll
    for (int r = 0; r < 8; ++r) ist[g + r * 65536] = 0.0f;
    if (g < 3072) vio[g] = (g < 2048) ? 0.0f : -3.0e38f;

    if (g < NB * NI) {   // encoder cell (b, ci)
        const int b = g >> 4, ci = g & 15;
        float xv = x[b * ND + (ci & 7)];
        float c = (ci < 8) ? __fmul_rn(50.0f, xv) : __fmul_rn(-50.0f, xv);
        c = fmaxf(c, 0.0f);
        float ev = 0.0f;
        for (int t = 0; t < NT; ++t) {
            ev = __fadd_rn(ev, __fmul_rn(0.1f, __fsub_rn(c, ev)));
            float z = (__fsub_rn(ev, 1.0f) > 0.0f) ? 1.0f : 0.0f;
            xsp[t * (NB * NI) + g] = (z > 0.0f) ? (char)1 : (char)0;
            ev = (z > 0.0f) ? 0.0f : ev;
        }
    }
}

// xs[0] -> Z buffer 0 extension chunk (kk=32, k_in 0..15)
__global__ __launch_bounds__(256) void k_init2(char* __restrict__ wsb) {
    const int b = threadIdx.x;                       // 256 threads
    char* zb0 = wsb + OFF_ZB;
    const char* xsp = wsb + OFF_XS;
    i32x4 xv = *(const i32x4*)(xsp + b * 16);
    unsigned dst = (((unsigned)(b >> 4)) * KK2 + 32u) * 1024u + (unsigned)(b & 15) * 16u;
    *(i32x4*)(zb0 + dst) = xv;
}

__global__ __launch_bounds__(NTHR, 2) void k_step(const float* __restrict__ w_out,
                                                  char* __restrict__ wsb, int t) {
    __shared__ float red[4 * 64 * 34];   // 4 k-partial buffers (two-phase reduce)
    __shared__ float z_s[64 * 34];
    __shared__ float w_out_lds[128];

    const int tid = threadIdx.x;
    const int beta = blockIdx.x;
    const int xcd = beta & 7, jb = beta >> 3;
    const int ht = xcd * 8 + (jb & 7);   // 0..63 (h-tile, XCD-contiguous weights)
    const int bt = jb >> 3;              // 0..3
    const int b0 = bt * 64, h0 = ht * 32;

    const char* w4 = wsb + OFF_W4;
    const float* inv_scale = (const float*)(wsb + OFF_SC);
    char* zb = wsb + OFF_ZB;
    const char* xsp = wsb + OFF_XS;
    float* vst = (float*)(wsb + OFF_V);
    float* ist = (float*)(wsb + OFF_I);
    float* pio = (float*)(wsb + OFF_PIO);
    float* vio = (float*)(wsb + OFF_VIO);

    const char* zr = zb + (t & 1) * ZBUF_B;
    char* zw = zb + ((t + 1) & 1) * ZBUF_B;

    // LI readout update for step t-1 (stream-ordered)
    const int g = beta * NTHR + tid;
    if (t > 0 && g < NB * NO) {
        const float* pr = pio + ((t - 1) & 1) * (NB * 64 * NO);
        const int b = g >> 2, o = g & 3;
        float s = 0.0f;
        #pragma unroll
        for (int jj = 0; jj < 64; ++jj) s += pr[(b * 64 + jj) * NO + o];
        float vo = vio[g], io = vio[1024 + g], mx = vio[2048 + g];
        float von = __fadd_rn(vo, __fmul_rn(0.1f, __fsub_rn(io, vo)));  // old io
        io = __fadd_rn(__fmul_rn(io, 0.8f), s);
        vio[g] = von; vio[1024 + g] = io; vio[2048 + g] = fmaxf(mx, von);
    }

    // xs[t+1] -> next Z extension (kk=32)
    if (ht == 0 && t + 1 < NT && tid < 64) {
        int bg = b0 + tid;
        i32x4 xv = *(const i32x4*)(xsp + ((t + 1) * NB + bg) * 16);
        unsigned dst = (((unsigned)(bg >> 4)) * KK2 + 32u) * 1024u
                     + (unsigned)(bg & 15) * 16u;
        *(i32x4*)(zw + dst) = xv;
    }
    if (tid < 128) w_out_lds[tid] = w_out[(tid >> 5) * NH + h0 + (tid & 31)];

    // ---- i8 MFMA GEMM: waves split K chunks by kk%8; 4 splits, K=64 per chunk
    const int w = tid >> 6, lane = tid & 63;
    const unsigned h16a = (unsigned)(ht * 2);

    i32x4 acc[4][2][4];   // [rb][hb][split]
    #pragma unroll
    for (int rb = 0; rb < 4; ++rb)
        #pragma unroll
        for (int hb = 0; hb < 2; ++hb)
            #pragma unroll
            for (int sp = 0; sp < 4; ++sp) acc[rb][hb][sp] = (i32x4){0, 0, 0, 0};

    for (int kk = w; kk < KK2; kk += 8) {
        i64x2 a[4];
        #pragma unroll
        for (int rb = 0; rb < 4; ++rb) {
            unsigned off = (((unsigned)(bt * 4 + rb)) * KK2 + (unsigned)kk) * 1024u
                         + (unsigned)lane * 16u;
            a[rb] = *(const i64x2*)(zr + off);
        }
        #pragma unroll
        for (int sp = 0; sp < 4; ++sp) {
            #pragma unroll
            for (int hb = 0; hb < 2; ++hb) {
                unsigned off = (unsigned)sp * SSTR
                             + ((h16a + (unsigned)hb) * KK2 + (unsigned)kk) * 1024u
                             + (unsigned)lane * 16u;
                i64x2 bfr = *(const i64x2*)(w4 + off);
                #pragma unroll
                for (int rb = 0; rb < 4; ++rb) {
                    acc[rb][hb][sp] = __builtin_amdgcn_mfma_i32_16x16x32_i8(
                        a[rb][0], bfr[0], acc[rb][hb][sp], 0, 0, 0);
                    acc[rb][hb][sp] = __builtin_amdgcn_mfma_i32_16x16x32_i8(
                        a[rb][1], bfr[1], acc[rb][hb][sp], 0, 0, 0);
                }
            }
        }
    }

    // combine splits -> f32, two-phase cross-wave reduce
    const int lk = lane >> 4, lh = lane & 15;
    const float inv0 = inv_scale[h0 + lh], inv1 = inv_scale[h0 + 16 + lh];
    float fc[4][2][4];
    #pragma unroll
    for (int rb = 0; rb < 4; ++rb)
        #pragma unroll
        for (int hb = 0; hb < 2; ++hb) {
            float invs = hb ? inv1 : inv0;
            #pragma unroll
            for (int r = 0; r < 4; ++r) {
                float f = fmaf((float)acc[rb][hb][3][r], 16777216.0f,
                          fmaf((float)acc[rb][hb][2][r], 65536.0f,
                          fmaf((float)acc[rb][hb][1][r], 256.0f,
                               (float)acc[rb][hb][0][r])));
                fc[rb][hb][r] = f * invs;
            }
        }
    if (w >= 4) {
        #pragma unroll
        for (int rb = 0; rb < 4; ++rb)
            #pragma unroll
            for (int hb = 0; hb < 2; ++hb)
                #pragma unroll
                for (int r = 0; r < 4; ++r)
                    red[(w - 4) * 2176 + (rb * 16 + lk * 4 + r) * 34 + hb * 16 + lh]
                        = fc[rb][hb][r];
    }
    __syncthreads();
    if (w < 4) {
        #pragma unroll
        for (int rb = 0; rb < 4; ++rb)
            #pragma unroll
            for (int hb = 0; hb < 2; ++hb)
                #pragma unroll
                for (int r = 0; r < 4; ++r) {
                    int ro = w * 2176 + (rb * 16 + lk * 4 + r) * 34 + hb * 16 + lh;
                    red[ro] = fc[rb][hb][r] + red[ro];
                }
    }
    __syncthreads();

    // reduce 4 buffers + LIF update (4 elems/thread)
    #pragma unroll
    for (int e = 0; e < 4; ++e) {
        int idx = e * NTHR + tid;
        int bl = idx >> 5, hl = idx & 31;
        int ro = bl * 34 + hl;
        float accv = ((red[ro] + red[2176 + ro]) + red[2 * 2176 + ro]) + red[3 * 2176 + ro];
        int gidx = (b0 + bl) * NH + h0 + hl;
        float vv = vst[gidx], ii = ist[gidx];
        float vd = __fadd_rn(vv, __fmul_rn(0.1f, __fsub_rn(ii, vv)));
        float zn = (__fsub_rn(vd, 1.0f) > 0.0f) ? 1.0f : 0.0f;
        vst[gidx] = (zn > 0.0f) ? 0.0f : vd;
        ist[gidx] = __fadd_rn(__fmul_rn(ii, 0.8f), accv);
        z_s[ro] = zn;
    }
    __syncthreads();

    if (tid < 256) {
        // spikes -> Z (i8, fragment-linear; this block owns chunk kk=ht>>1, quads by ht&1)
        int b = tid >> 2, c = tid & 3;
        int bg = b0 + b;
        unsigned lo_u = 0, hi_u = 0;
        #pragma unroll
        for (int jj = 0; jj < 4; ++jj)
            lo_u |= (z_s[b * 34 + c * 8 + jj] > 0.5f ? 1u : 0u) << (jj * 8);
        #pragma unroll
        for (int jj = 0; jj < 4; ++jj)
            hi_u |= (z_s[b * 34 + c * 8 + 4 + jj] > 0.5f ? 1u : 0u) << (jj * 8);
        unsigned q = (unsigned)((ht & 1) * 2 + (c >> 1));
        unsigned dst = (((unsigned)(bg >> 4)) * KK2 + (unsigned)(ht >> 1)) * 1024u
                     + (q * 16u + (unsigned)(bg & 15)) * 16u + (unsigned)((c & 1) * 8);
        *(u32x2*)(zw + dst) = (u32x2){lo_u, hi_u};

        // readout partial: sum over this block's 32 h per (b, o)
        int o = tid & 3;
        float s = 0.0f;
        #pragma unroll
        for (int h = 0; h < 32; ++h)
            s = fmaf(z_s[b * 34 + h], w_out_lds[o * 32 + h], s);
        float* pw = pio + (t & 1) * (NB * 64 * NO);
        pw[((b0 + b) * 64 + ht) * NO + o] = s;
    }
}

__global__ __launch_bounds__(256) void k_final(char* __restrict__ wsb,
                                               float* __restrict__ out) {
    const int g = blockIdx.x * 256 + threadIdx.x;   // 1024 threads
    if (g >= NB * NO) return;
    float* vio = (float*)(wsb + OFF_VIO);
    float vo = vio[g], io = vio[1024 + g], mx = vio[2048 + g];
    float von = __fadd_rn(vo, __fmul_rn(0.1f, __fsub_rn(io, vo)));
    mx = fmaxf(mx, von);

    float mm = fmaxf(mx, __shfl_xor(mx, 1, 64));
    mm = fmaxf(mm, __shfl_xor(mm, 2, 64));
    float e = expf(__fsub_rn(mx, mm));
    float es = e;
    es += __shfl_xor(es, 1, 64);
    es += __shfl_xor(es, 2, 64);
    out[g] = e / es;
}

extern "C" void kernel_launch(void* const* d_in, const int* in_sizes, int n_in,
                              void* d_out, int out_size, void* d_ws, size_t ws_size,
                              hipStream_t stream) {
    const float* x     = (const float*)d_in[0];
    const float* w_in  = (const float*)d_in[1];
    const float* w_rec = (const float*)d_in[2];
    const float* w_out = (const float*)d_in[3];
    float* out = (float*)d_out;
    char* wsb  = (char*)d_ws;

    k_scale<<<256, 512, 0, stream>>>(w_rec, w_in, wsb);
    k_pack<<<NH, 192, 0, stream>>>(w_rec, w_in, wsb);
    k_init<<<256, 256, 0, stream>>>(x, wsb);
    k_init2<<<1, 256, 0, stream>>>(wsb);
    for (int t = 0; t < NT; ++t)
        k_step<<<256, NTHR, 0, stream>>>(w_out, wsb, t);
    k_final<<<4, 256, 0, stream>>>(wsb, out);
}